// Round 9
// baseline (1753.741 us; speedup 1.0000x reference)
//
#include <hip/hip_runtime.h>
#include <math.h>

constexpr int NY_ = 320, NX_ = 320, NT_ = 160, SHOTS_ = 2, NSRC_ = 8, NREC_ = 96;
constexpr float DT_  = 4.0e-4f;
constexpr float C1_  = 9.0f / 8.0f;
constexpr float C2_  = -1.0f / 24.0f;
constexpr float IDH_ = 0.25f;           // 1/DH, exact
constexpr int NP_     = NY_ * NX_;
constexpr int NSTRIP_ = 40;             // 8-row strips per shot
constexpr int NBLK_   = SHOTS_ * NSTRIP_;
// ws layout (float words): stress mirrors [buf2][field3: syy,sxy,sxx][shot2][NP],
// receiver traces, per-side flags (monotonic round counters).
constexpr int REC_OFF_ = 12 * NP_;
constexpr int FLG_OFF_ = REC_OFF_ + SHOTS_ * NREC_ * NT_;   // flgU[80] then flgD[80]
constexpr int WS_WORDS_ = FLG_OFF_ + 256;
constexpr int IMP_ROWS_  = 18;                 // syy 7 + sxy 7 + ghost sxx 4
constexpr int IMP_ELEMS_ = IMP_ROWS_ * NX_;    // 5760

// ---- coherent (IF-backed) access: relaxed agent-scope atomics ----
__device__ __forceinline__ float cld(const float* p) {
    return __hip_atomic_load(p, __ATOMIC_RELAXED, __HIP_MEMORY_SCOPE_AGENT);
}
__device__ __forceinline__ void cst(float* p, float v) {
    __hip_atomic_store(p, v, __ATOMIC_RELAXED, __HIP_MEMORY_SCOPE_AGENT);
}
__device__ __forceinline__ unsigned cldu(const unsigned* p) {
    return __hip_atomic_load(p, __ATOMIC_RELAXED, __HIP_MEMORY_SCOPE_AGENT);
}
__device__ __forceinline__ void cstu(unsigned* p, unsigned v) {
    __hip_atomic_store(p, v, __ATOMIC_RELAXED, __HIP_MEMORY_SCOPE_AGENT);
}

// guarded halo import load: out-of-grid rows read 0 (== masked border equivalence)
__device__ __forceinline__ float gldf(const float* p, int y, int c) {
    return ((unsigned)y < (unsigned)NY_) ? cld(p + y * NX_ + c) : 0.0f;
}
// guarded LDS x-tap: out-of-grid cols read 0
__device__ __forceinline__ float ltap(const float (*A)[NX_], int ly, int c) {
    return ((unsigned)c < (unsigned)NX_) ? A[ly][c] : 0.0f;
}
// register x-tap via wave shuffle (cells are 64-col interleaved, 5 groups/lane)
__device__ __forceinline__ float shtap(float cur, float adj, int lane, int dx) {
    int idx = (lane + dx) & 63;
    float a = __shfl(cur, idx, 64);
    float b = __shfl(adj, idx, 64);
    return ((unsigned)(lane + dx) < 64u) ? a : b;
}

__device__ __forceinline__ float pml_by(int gy) {
    const double d0 = 3.0 * 1600.0 * log(1000.0) / (2.0 * 20.0 * 4.0);
    double py = 0.0;
    if (gy < 20)             { double u = (20.0 - gy) / 20.0;           py = u * u; }
    else if (gy >= NY_ - 20) { double u = (gy - (NY_ - 1 - 20)) / 20.0; py = u * u; }
    return (float)exp(-d0 * py * 4.0e-4);
}

__device__ __forceinline__ unsigned long long srcmask(const int* __restrict__ src_loc,
                                                      int s, int gy, int lane) {
    unsigned long long sm = 0ull;
    if ((unsigned)gy < (unsigned)NY_) {
        for (int js = 0; js < NSRC_; ++js) {
            int sy = src_loc[(s * NSRC_ + js) * 2 + 0];
            int sx = src_loc[(s * NSRC_ + js) * 2 + 1];
            if (sy == gy && (sx & 63) == lane) sm |= 1ull << (8 * (sx >> 6) + js);
        }
    }
    return sm;
}

// x-CPML static sparsity: groups k=1,2,3 (cols 64..255) have bx=1 -> x memory vars
// stay exactly 0 forever -> packed [2] arrays hold only k=0,k=4. Bit-exact.

// ---- owned-row velocity + CPML update (self sxx in registers, shuffle x-taps) ----
__device__ __forceinline__ void vrow(
    int lane, const float* __restrict__ ampsT,
    float (&VY)[5], float (&VX)[5],
    float (&MS1)[5], float (&MS2)[5], float (&MS3)[2], float (&MS4)[2], // msyyy,msxyy,msxyx,msxxx
    const float (&SXX)[5],
    int lyS, int lxS, int lv,
    float by, const float (&bx2)[2], const float (&bxm12)[2],
    const float* __restrict__ buRow, float mr, const float (&mkc2)[2],
    unsigned long long sm,
    const float (*Lsyy)[NX_], const float (*Lsxy)[NX_],
    float (*Lvy)[NX_], float (*Lvx)[NX_])
{
    const float bym1 = by - 1.0f;
    #pragma unroll
    for (int k = 0; k < 5; ++k) {
        const int c = 64 * k + lane;
        const bool px = (k == 0 || k == 4);
        const int xk = (k == 0) ? 0 : 1;
        const float mk = mr * (px ? mkc2[xk] : 1.0f);
        const float buk = buRow[c];
        // D-_y(syy)
        float d = (C1_ * (Lsyy[lyS][c] - Lsyy[lyS - 1][c])
                 + C2_ * (Lsyy[lyS + 1][c] - Lsyy[lyS - 2][c])) * IDH_;
        MS1[k] = by * MS1[k] + bym1 * d;
        float ay = d + MS1[k];
        // D+_x(sxy)
        d = (C1_ * (ltap(Lsxy, lxS, c + 1) - Lsxy[lxS][c])
           + C2_ * (ltap(Lsxy, lxS, c + 2) - ltap(Lsxy, lxS, c - 1))) * IDH_;
        if (px) { MS3[xk] = bx2[xk] * MS3[xk] + bxm12[xk] * d; ay += d + MS3[xk]; }
        else    { ay += d; }
        VY[k] = VY[k] + DT_ * buk * ay;
        unsigned m = (unsigned)(sm >> (8 * k)) & 0xFFu;
        if (m) {
            for (int js = 0; js < NSRC_; ++js)
                if (m & (1u << js)) VY[k] += DT_ * ampsT[js * NT_] * buk;
        }
        VY[k] *= mk;
        // D-_x(sxx) via register shuffles
        const float sxxp = (k < 4) ? SXX[k + 1] : 0.0f;
        const float sxxm = (k > 0) ? SXX[k - 1] : 0.0f;
        d = (C1_ * (SXX[k] - shtap(SXX[k], sxxm, lane, -1))
           + C2_ * (shtap(SXX[k], sxxp, lane, 1) - shtap(SXX[k], sxxm, lane, -2))) * IDH_;
        float ax;
        if (px) { MS4[xk] = bx2[xk] * MS4[xk] + bxm12[xk] * d; ax = d + MS4[xk]; }
        else    { ax = d; }
        // D+_y(sxy)
        d = (C1_ * (Lsxy[lxS + 1][c] - Lsxy[lxS][c])
           + C2_ * (Lsxy[lxS + 2][c] - Lsxy[lxS - 1][c])) * IDH_;
        MS2[k] = by * MS2[k] + bym1 * d;
        ax += d + MS2[k];
        VX[k] = (VX[k] + DT_ * buk * ax) * mk;
        Lvy[lv][c] = VY[k]; Lvx[lv][c] = VX[k];
    }
}

// ---- ghost-row velocity + CPML update (sxx taps from LDS mirror row) ----
__device__ __forceinline__ void vrowG(
    int lane, const float* __restrict__ ampsT,
    float (&VY)[5], float (&VX)[5],
    float (&MS1)[5], float (&MS2)[5], float (&MS3)[2], float (&MS4)[2],
    const float (*SXXL)[NX_], int gr,
    int lyS, int lxS, int lv,
    float by, const float (&bx2)[2], const float (&bxm12)[2],
    const float* __restrict__ buRow, float mr, const float (&mkc2)[2],
    unsigned long long sm,
    const float (*Lsyy)[NX_], const float (*Lsxy)[NX_],
    float (*Lvy)[NX_], float (*Lvx)[NX_])
{
    const float bym1 = by - 1.0f;
    #pragma unroll
    for (int k = 0; k < 5; ++k) {
        const int c = 64 * k + lane;
        const bool px = (k == 0 || k == 4);
        const int xk = (k == 0) ? 0 : 1;
        const float mk = mr * (px ? mkc2[xk] : 1.0f);
        const float buk = buRow[c];
        // D-_y(syy)
        float d = (C1_ * (Lsyy[lyS][c] - Lsyy[lyS - 1][c])
                 + C2_ * (Lsyy[lyS + 1][c] - Lsyy[lyS - 2][c])) * IDH_;
        MS1[k] = by * MS1[k] + bym1 * d;
        float ay = d + MS1[k];
        // D+_x(sxy)
        d = (C1_ * (ltap(Lsxy, lxS, c + 1) - Lsxy[lxS][c])
           + C2_ * (ltap(Lsxy, lxS, c + 2) - ltap(Lsxy, lxS, c - 1))) * IDH_;
        if (px) { MS3[xk] = bx2[xk] * MS3[xk] + bxm12[xk] * d; ay += d + MS3[xk]; }
        else    { ay += d; }
        VY[k] = VY[k] + DT_ * buk * ay;
        unsigned m = (unsigned)(sm >> (8 * k)) & 0xFFu;
        if (m) {
            for (int js = 0; js < NSRC_; ++js)
                if (m & (1u << js)) VY[k] += DT_ * ampsT[js * NT_] * buk;
        }
        VY[k] *= mk;
        // D-_x(sxx) from LDS mirror row (identical values to the register path)
        d = (C1_ * (SXXL[gr][c] - ltap(SXXL, gr, c - 1))
           + C2_ * (ltap(SXXL, gr, c + 1) - ltap(SXXL, gr, c - 2))) * IDH_;
        float ax;
        if (px) { MS4[xk] = bx2[xk] * MS4[xk] + bxm12[xk] * d; ax = d + MS4[xk]; }
        else    { ax = d; }
        // D+_y(sxy)
        d = (C1_ * (Lsxy[lxS + 1][c] - Lsxy[lxS][c])
           + C2_ * (Lsxy[lxS + 2][c] - Lsxy[lxS - 1][c])) * IDH_;
        MS2[k] = by * MS2[k] + bym1 * d;
        ax += d + MS2[k];
        VX[k] = (VX[k] + DT_ * buk * ax) * mk;
        Lvy[lv][c] = VY[k]; Lvx[lv][c] = VX[k];
    }
}

__global__ void init_kernel(float* __restrict__ ws) {
    for (int i = blockIdx.x * 256 + threadIdx.x; i < WS_WORDS_; i += gridDim.x * 256)
        ws[i] = 0.0f;
}

__global__ __launch_bounds__(512)
void elastic_kernel(const float* __restrict__ lamb, const float* __restrict__ mu,
                    const float* __restrict__ buoy, const float* __restrict__ amps,
                    const int* __restrict__ src_loc, const int* __restrict__ rec_loc,
                    float* __restrict__ out, float* __restrict__ ws)
{
    // LDS row maps: Lvy/Lvx: y -> y+2 (rows -2..9)
    //               Lsyy:    y -> y+4 (rows -4..10)
    //               Lsxy:    y -> y+3 (rows -3..11)
    //               Lsxxg:   ghost sxx rows {-2,-1,8,9} -> {0,1,2,3}
    __shared__ float Lvy[12][NX_], Lvx[12][NX_], Lsyy[15][NX_], Lsxy[15][NX_], Lsxxg[4][NX_];
    __shared__ unsigned ctrU, ctrD;   // monotonic per-side publish counters

    const int tid  = threadIdx.x;
    const int lane = tid & 63;
    const int w    = tid >> 6;          // owned row 0..7 (one wave per row)
    const int bid  = blockIdx.x;
    const int s    = bid / NSTRIP_;
    const int j    = bid % NSTRIP_;
    const int r0   = j * 8;
    const int gy   = r0 + w;

    unsigned* flgU = (unsigned*)(ws + FLG_OFF_);          // rows 0..3 published
    unsigned* flgD = flgU + NBLK_;                        // rows 4..7 published
    const int sbase = s * NSTRIP_;
    float* recp = ws + REC_OFF_ + (s * NREC_ + tid) * NT_;   // valid only if tid<96
    const float* ampsS = amps + s * NSRC_ * NT_;

    // ghost-row assignment (round-1 proven): waves 0,1 -> rows -2,-1; waves 6,7 -> 8,9
    const bool isE = (w < 2) || (w >= 6);
    const int  yE  = (w < 2) ? (w - 2) : (w + 2);
    const int  gyE = r0 + yE;
    const bool hasE = isE && ((unsigned)gyE < (unsigned)NY_);
    const int lySE = yE + 4, lxSE = yE + 3, lvE = yE + 2;
    const int grE  = (w < 2) ? w : (w - 4);   // Lsxxg row for ghost {-2,-1,8,9}->{0,1,2,3}
    const int cEr = hasE ? gyE : 0;

    // material row base pointers (wave-uniform -> SGPR; regular cached loads)
    const float* buO_p = buoy + gy * NX_;
    const float* laO_p = lamb + gy * NX_;
    const float* muO_p = mu   + gy * NX_;
    const float* buE_p = buoy + cEr * NX_;

    // per-row wave-uniform scalars
    const float by   = pml_by(gy);
    const float bym1 = by - 1.0f;
    const float byE  = pml_by(gyE);
    const float mrO  = (gy  >= 2 && gy  < NY_ - 2) ? 1.0f : 0.0f;
    const float mrE  = (gyE >= 2 && gyE < NY_ - 2) ? 1.0f : 0.0f;

    const double d0 = 3.0 * 1600.0 * log(1000.0) / (2.0 * 20.0 * 4.0);
    float bx2[2], bxm12[2], mkc2[2];
    #pragma unroll
    for (int e = 0; e < 2; ++e) {
        int c = (e == 0) ? lane : 256 + lane;   // groups k=0 and k=4
        double pxd = 0.0;
        if (c < 20)             { double u = (20.0 - c) / 20.0;           pxd = u * u; }
        else if (c >= NX_ - 20) { double u = (c - (NX_ - 1 - 20)) / 20.0; pxd = u * u; }
        bx2[e] = (float)exp(-d0 * pxd * 4.0e-4);
        bxm12[e] = bx2[e] - 1.0f;
        mkc2[e] = (c >= 2 && c < NX_ - 2) ? 1.0f : 0.0f;
    }

    const unsigned long long smO = srcmask(src_loc, s, gy, lane);
    const unsigned long long smE = hasE ? srcmask(src_loc, s, gyE, lane) : 0ull;

    // per-thread receiver (tid<96 handles receiver tid of this shot)
    bool myrec = false; int rl = 0;
    if (tid < NREC_) {
        int ry = rec_loc[(s * NREC_ + tid) * 2 + 0];
        int rx = rec_loc[(s * NREC_ + tid) * 2 + 1];
        if ((ry >> 3) == j) { myrec = true; rl = ((ry & 7) + 2) * NX_ + rx; }
    }

    // zero LDS (fields start at 0)
    for (int i = tid; i < 15 * NX_; i += 512) {
        if (i < 12 * NX_) { ((float*)Lvy)[i] = 0.f; ((float*)Lvx)[i] = 0.f; }
        if (i < 4 * NX_)  { ((float*)Lsxxg)[i] = 0.f; }
        ((float*)Lsyy)[i] = 0.f; ((float*)Lsxy)[i] = 0.f;
    }
    if (tid == 0) { ctrU = 0u; ctrD = 0u; }

    // ---- register state (x-CPML packed); ghost state in edge waves ----
    float vy[5] = {}, vx[5] = {}, syy[5] = {}, sxy[5] = {}, sxx[5] = {};
    float msyyy[5] = {}, msxyy[5] = {}, msxyx[2] = {}, msxxx[2] = {};
    float mvyy[5] = {}, mvyx[2] = {}, mvxy[5] = {}, mvxx[2] = {};
    float vyE[5] = {}, vxE[5] = {};
    float msyyyE[5] = {}, msxyyE[5] = {}, msxyxE[2] = {}, msxxxE[2] = {};

    __syncthreads();

    for (int t = 0; t < NT_; ++t) {
        const int rb = t & 1, wb = rb ^ 1;   // ping-pong stress mirrors, flag-gated
        const float* rSyy = ws + ((rb * 3 + 0) * SHOTS_ + s) * NP_;
        const float* rSxy = ws + ((rb * 3 + 1) * SHOTS_ + s) * NP_;
        const float* rSxx = ws + ((rb * 3 + 2) * SHOTS_ + s) * NP_;
        float* wSyy = ws + ((wb * 3 + 0) * SHOTS_ + s) * NP_;
        float* wSxy = ws + ((wb * 3 + 1) * SHOTS_ + s) * NP_;
        float* wSxx = ws + ((wb * 3 + 2) * SHOTS_ + s) * NP_;

        // ======== poll per-side flags (wave 0; usually already set) ========
        __syncthreads();
        if (tid < 64) {
            for (;;) {
                bool ok = true;
                if (tid == 0 && j > 0)                ok = cldu(&flgD[sbase + j - 1]) >= (unsigned)t;
                else if (tid == 1 && j < NSTRIP_ - 1) ok = cldu(&flgU[sbase + j + 1]) >= (unsigned)t;
                if (__all(ok)) break;
                __builtin_amdgcn_s_sleep(1);
            }
        }
        __syncthreads();
        asm volatile("" ::: "memory");

        // ======== import: 18 halo rows spread flat over ALL 512 threads ========
        // rows 0..6: syy offsets {-4..-1, 8..10}; 7..13: sxy {-3..-1, 8..11};
        // 14..17: ghost sxx {-2,-1,8,9}. All loads issued before any LDS write.
        {
            float A[12];
            #pragma unroll
            for (int i = 0; i < 12; ++i) {
                const int e = tid + 512 * i;
                A[i] = 0.0f;
                if (e < IMP_ELEMS_) {
                    const int r = e / NX_, c = e - r * NX_;
                    if (r < 7) {
                        A[i] = gldf(rSyy, r0 + ((r < 4) ? r - 4 : r + 4), c);
                    } else if (r < 14) {
                        const int q = r - 7;
                        A[i] = gldf(rSxy, r0 + ((q < 3) ? q - 3 : q + 5), c);
                    } else {
                        const int q = r - 14;
                        A[i] = gldf(rSxx, r0 + ((q < 2) ? q - 2 : q + 6), c);
                    }
                }
            }
            #pragma unroll
            for (int i = 0; i < 12; ++i) {
                const int e = tid + 512 * i;
                if (e < IMP_ELEMS_) {
                    const int r = e / NX_, c = e - r * NX_;
                    if (r < 7)       Lsyy[(r < 4) ? r : r + 8][c] = A[i];
                    else if (r < 14) { const int q = r - 7;  Lsxy[(q < 3) ? q : q + 8][c] = A[i]; }
                    else             { const int q = r - 14; Lsxxg[q][c] = A[i]; }
                }
            }
        }
        __syncthreads();   // (A) halos ready

        // ======== velocity: all waves owned row; edge waves also ghost row ========
        vrow(lane, ampsS + t, vy, vx, msyyy, msxyy, msxyx, msxxx, sxx,
             w + 4, w + 3, w + 2, by, bx2, bxm12, buO_p, mrO, mkc2, smO,
             Lsyy, Lsxy, Lvy, Lvx);
        if (hasE)
            vrowG(lane, ampsS + t, vyE, vxE, msyyyE, msxyyE, msxyxE, msxxxE,
                  Lsxxg, grE, lySE, lxSE, lvE, byE, bx2, bxm12, buE_p, mrE, mkc2, smE,
                  Lsyy, Lsxy, Lvy, Lvx);
        __syncthreads();   // (C) all velocity rows -2..9 current

        // record receivers (strip-local)
        if (myrec) recp[t] = ((const float*)Lvy)[rl];

        // ======== stress (owned rows) + inline publish + per-side EARLY flag ========
        {
            const int lv = w + 2;
            #pragma unroll
            for (int k = 0; k < 5; ++k) {
                const int c = 64 * k + lane;
                const bool px = (k == 0 || k == 4);
                const int xk = (k == 0) ? 0 : 1;
                const float mk = mrO * (px ? mkc2[xk] : 1.0f);
                const float lak = laO_p[c];
                const float muk = muO_p[c];
                float d, e1, e2, g;
                // D+_y(vy)
                d = (C1_ * (Lvy[lv + 1][c] - vy[k]) + C2_ * (Lvy[lv + 2][c] - Lvy[lv - 1][c])) * IDH_;
                mvyy[k] = by * mvyy[k] + bym1 * d;
                e1 = d + mvyy[k];
                // D-_x(vx)
                d = (C1_ * (vx[k] - ltap(Lvx, lv, c - 1))
                   + C2_ * (ltap(Lvx, lv, c + 1) - ltap(Lvx, lv, c - 2))) * IDH_;
                if (px) { mvxx[xk] = bx2[xk] * mvxx[xk] + bxm12[xk] * d; e2 = d + mvxx[xk]; }
                else    { e2 = d; }
                const float l2m = lak + 2.0f * muk;
                syy[k] = (syy[k] + DT_ * (l2m * e1 + lak * e2)) * mk;
                sxx[k] = (sxx[k] + DT_ * (l2m * e2 + lak * e1)) * mk;
                // D+_x(vy)
                d = (C1_ * (ltap(Lvy, lv, c + 1) - vy[k])
                   + C2_ * (ltap(Lvy, lv, c + 2) - ltap(Lvy, lv, c - 1))) * IDH_;
                if (px) { mvyx[xk] = bx2[xk] * mvyx[xk] + bxm12[xk] * d; g = d + mvyx[xk]; }
                else    { g = d; }
                // D-_y(vx)
                d = (C1_ * (vx[k] - Lvx[lv - 1][c]) + C2_ * (Lvx[lv + 1][c] - Lvx[lv - 2][c])) * IDH_;
                mvxy[k] = by * mvxy[k] + bym1 * d;
                g = g + d + mvxy[k];
                sxy[k] = (sxy[k] + DT_ * muk * g) * mk;
                Lsyy[w + 4][c] = syy[k];
                Lsxy[w + 3][c] = sxy[k];
                // publish exactly the rows neighbors import:
                // syy rows {0..7}\{3}, sxy {0..7}\{4}, sxx {0,1,6,7}
                if (w != 3) cst(&wSyy[gy * NX_ + c], syy[k]);
                if (w != 4) cst(&wSxy[gy * NX_ + c], sxy[k]);
                if (isE)    cst(&wSxx[gy * NX_ + c], sxx[k]);
            }
            // per-wave drain of own publishes, then monotonic side counter; the
            // 4th wave of a side sets that side's flag — BEFORE the block barrier,
            // so neighbors start their poll+import while we finish the step.
            asm volatile("s_waitcnt vmcnt(0)" ::: "memory");
            if (lane == 0) {
                unsigned old = atomicAdd((w < 4) ? &ctrU : &ctrD, 1u);
                if (old == 4u * (unsigned)t + 3u) {
                    if (w < 4) cstu(&flgU[sbase + j], (unsigned)(t + 1));
                    else       cstu(&flgD[sbase + j], (unsigned)(t + 1));
                }
            }
        }
        __syncthreads();   // (F) LDS stress rows visible for next step's taps
    }

    // ---------- final output: out[s][r][t] = 0.5*(rec[t] + rec[t+1]) ----------
    if (myrec) {
        float* op = out + (s * NREC_ + tid) * (NT_ - 1);
        for (int t = 0; t < NT_ - 1; ++t) op[t] = 0.5f * (recp[t] + recp[t + 1]);
    }
}

extern "C" void kernel_launch(void* const* d_in, const int* in_sizes, int n_in,
                              void* d_out, int out_size, void* d_ws, size_t ws_size,
                              hipStream_t stream)
{
    const float* lamb = (const float*)d_in[0];
    const float* mu   = (const float*)d_in[1];
    const float* buoy = (const float*)d_in[2];
    const float* amps = (const float*)d_in[3];
    const int*   src  = (const int*)d_in[4];
    const int*   recl = (const int*)d_in[5];
    float* out = (float*)d_out;
    float* ws  = (float*)d_ws;

    init_kernel<<<dim3(512), dim3(256), 0, stream>>>(ws);
    elastic_kernel<<<dim3(NBLK_), dim3(512), 0, stream>>>(lamb, mu, buoy, amps, src, recl, out, ws);
}